// Round 4
// baseline (363.832 us; speedup 1.0000x reference)
//
#include <hip/hip_runtime.h>
#include <math.h>

#define EPS 1e-16f
__device__ __forceinline__ float lrelu(float v) { return v > 0.0f ? v : 0.2f * v; }

// ---------------- CSR build ----------------
__global__ void k_zero(int* __restrict__ deg, int N) {
    int i = blockIdx.x * 256 + threadIdx.x;
    if (i < N) deg[i] = 0;
}

__global__ void k_deg(const int* __restrict__ dst, int* __restrict__ deg, int E) {
    int e = blockIdx.x * 256 + threadIdx.x;
    if (e < E) atomicAdd(&deg[dst[e]], 1);
}

// multi-block scan: per-block local inclusive scan + block sums
__global__ __launch_bounds__(1024) void k_scan_local(const int* __restrict__ deg,
                                                     int* __restrict__ rowptr,
                                                     int* __restrict__ blocksum, int N) {
    __shared__ int sdata[1024];
    int i = blockIdx.x * 1024 + threadIdx.x;
    int v = (i < N) ? deg[i] : 0;
    sdata[threadIdx.x] = v;
    __syncthreads();
    for (int off = 1; off < 1024; off <<= 1) {
        int t = (threadIdx.x >= (unsigned)off) ? sdata[threadIdx.x - off] : 0;
        __syncthreads();
        sdata[threadIdx.x] += t;
        __syncthreads();
    }
    if (i < N) rowptr[i + 1] = sdata[threadIdx.x];
    if (threadIdx.x == 1023) blocksum[blockIdx.x] = sdata[1023];
}

// exclusive scan of <=64 block sums in one wave
__global__ void k_scan_sums(const int* __restrict__ blocksum, int* __restrict__ blockoff, int nb) {
    int lane = threadIdx.x;
    int v = (lane < nb) ? blocksum[lane] : 0;
    int incl = v;
#pragma unroll
    for (int off = 1; off < 64; off <<= 1) {
        int t = __shfl_up(incl, off);
        if (lane >= off) incl += t;
    }
    if (lane < nb) blockoff[lane] = incl - v;
}

__global__ void k_scan_add(int* __restrict__ rowptr, const int* __restrict__ blockoff,
                           const int* __restrict__ deg, int* __restrict__ cursor, int N) {
    int i = blockIdx.x * 256 + threadIdx.x;
    if (i >= N) return;
    int val = rowptr[i + 1] + blockoff[i >> 10];
    rowptr[i + 1] = val;
    cursor[i] = val - deg[i];
    if (i == 0) rowptr[0] = 0;
}

__global__ void k_scatter(const int* __restrict__ src, const int* __restrict__ dst,
                          int* __restrict__ cursor, int* __restrict__ ssrc, int E) {
    int e = blockIdx.x * 256 + threadIdx.x;
    if (e >= E) return;
    int pos = atomicAdd(&cursor[dst[e]], 1);
    ssrc[pos] = src[e];
}

// ---------------- layer 1 GEMM: x[N,128] @ W1[128,64] -> h1, + attention dots ----------------
// No LDS: lane = output col, W column cached in 128 VGPRs, x row is wave-uniform
// (readfirstlane'd wave id -> s_load through scalar cache).
#define R1 16   // rows per wave
__global__ __launch_bounds__(256) void k_gemm1(
    const float* __restrict__ x, const float* __restrict__ W1,
    const float* __restrict__ att_src1, const float* __restrict__ att_dst1,
    float* __restrict__ h1, float* __restrict__ a_src1, float* __restrict__ a_dst1, int N) {
    int lane = threadIdx.x & 63;
    int wave = __builtin_amdgcn_readfirstlane((int)((blockIdx.x * 256 + threadIdx.x) >> 6));
    int r0 = wave * R1;
    if (r0 >= N) return;
    int r1 = min(r0 + R1, N);
    float w[128];
#pragma unroll
    for (int k = 0; k < 128; k++) w[k] = W1[k * 64 + lane];   // coalesced, L2-resident
    float as = att_src1[lane], ad = att_dst1[lane];
    for (int r = r0; r < r1; r++) {
        const float4* xr = (const float4*)(x + (size_t)r * 128);
        float acc = 0.0f;
#pragma unroll
        for (int k4 = 0; k4 < 32; k4++) {
            float4 xv = xr[k4];                                // uniform -> s_load
            acc = fmaf(xv.x, w[4 * k4 + 0], acc);
            acc = fmaf(xv.y, w[4 * k4 + 1], acc);
            acc = fmaf(xv.z, w[4 * k4 + 2], acc);
            acc = fmaf(xv.w, w[4 * k4 + 3], acc);
        }
        h1[(size_t)r * 64 + lane] = acc;
        float ps = acc * as, pd = acc * ad;
#pragma unroll
        for (int off = 4; off; off >>= 1) {
            ps += __shfl_down(ps, off, 8);
            pd += __shfl_down(pd, off, 8);
        }
        if ((lane & 7) == 0) {
            a_src1[r * 8 + (lane >> 3)] = ps;
            a_dst1[r * 8 + (lane >> 3)] = pd;
        }
    }
}

// ---------------- layer 1: per-dst-node softmax + aggregate (one wave per node) ----------------
// no max subtraction (softmax shift-invariant; logits are O(1))
__global__ __launch_bounds__(256) void k_node_agg1(
    const int* __restrict__ rowptr, const int* __restrict__ ssrc,
    const float* __restrict__ a_src1, const float* __restrict__ a_dst1,
    const float* __restrict__ h1, const float* __restrict__ bias1,
    float* __restrict__ xx, int N) {
    int d = (blockIdx.x * 256 + threadIdx.x) >> 6;
    int lane = threadIdx.x & 63;
    if (d >= N) return;
    int start = rowptr[d], end = rowptr[d + 1];
    int hcol = lane >> 3;   // head owning this output col
    int h8 = lane & 7;      // head this lane covers in edge-parallel phase
    int eoff = lane >> 3;   // edge-in-chunk this lane covers in edge-parallel phase
    float adst8 = a_dst1[d * 8 + h8];
    float acc0 = 0.0f, acc1 = 0.0f, lsumA = 0.0f;
    int base = start;
    for (; base + 8 <= end; base += 8) {
        // phase A: 8 edges x 8 heads in parallel
        int s_l = ssrc[base + eoff];
        float ex_l = __expf(lrelu(a_src1[(size_t)s_l * 8 + h8] + adst8));
        lsumA += ex_l;
        // phase B: broadcast (s,ex) via shuffle, 8 independent gathers
        int s0 = __shfl(s_l, 0),  s1 = __shfl(s_l, 8),  s2 = __shfl(s_l, 16), s3 = __shfl(s_l, 24);
        int s4 = __shfl(s_l, 32), s5 = __shfl(s_l, 40), s6 = __shfl(s_l, 48), s7 = __shfl(s_l, 56);
        float f0 = __shfl(ex_l, hcol),      f1 = __shfl(ex_l, 8 + hcol);
        float f2 = __shfl(ex_l, 16 + hcol), f3 = __shfl(ex_l, 24 + hcol);
        float f4 = __shfl(ex_l, 32 + hcol), f5 = __shfl(ex_l, 40 + hcol);
        float f6 = __shfl(ex_l, 48 + hcol), f7 = __shfl(ex_l, 56 + hcol);
        float g0 = h1[(size_t)s0 * 64 + lane], g1 = h1[(size_t)s1 * 64 + lane];
        float g2 = h1[(size_t)s2 * 64 + lane], g3 = h1[(size_t)s3 * 64 + lane];
        float g4 = h1[(size_t)s4 * 64 + lane], g5 = h1[(size_t)s5 * 64 + lane];
        float g6 = h1[(size_t)s6 * 64 + lane], g7 = h1[(size_t)s7 * 64 + lane];
        acc0 = fmaf(f0, g0, acc0); acc1 = fmaf(f1, g1, acc1);
        acc0 = fmaf(f2, g2, acc0); acc1 = fmaf(f3, g3, acc1);
        acc0 = fmaf(f4, g4, acc0); acc1 = fmaf(f5, g5, acc1);
        acc0 = fmaf(f6, g6, acc0); acc1 = fmaf(f7, g7, acc1);
    }
    int ecnt = end - base;
    if (ecnt > 0) {
        int s_l = 0; float ex_l = 0.0f;
        if (eoff < ecnt) {
            s_l = ssrc[base + eoff];
            ex_l = __expf(lrelu(a_src1[(size_t)s_l * 8 + h8] + adst8));
        }
        lsumA += ex_l;
        for (int j = 0; j < ecnt; j++) {
            int sj = __shfl(s_l, j * 8);
            float fj = __shfl(ex_l, j * 8 + hcol);
            acc0 = fmaf(fj, h1[(size_t)sj * 64 + lane], acc0);
        }
    }
    // denom: reduce lsumA over edge-offset bits (3..5); then broadcast head hcol's sum
    float t = lsumA;
    t += __shfl_xor(t, 8); t += __shfl_xor(t, 16); t += __shfl_xor(t, 32);
    float lsum = __shfl(t, hcol);
    float o = (acc0 + acc1) / (lsum + EPS) + bias1[lane];
    xx[(size_t)d * 64 + lane] = o > 0.0f ? o : expm1f(o);   // ELU
}

// ---------------- layer 2 GEMM fused with attention dots ----------------
// xx[N,64] @ W2[64,40] -> h2 ; a_src2/a_dst2 = h2 . att2  (all-lane xor reduce)
#define R2 16
__global__ __launch_bounds__(256) void k_gemm2(
    const float* __restrict__ xx, const float* __restrict__ W2,
    const float* __restrict__ att_src2, const float* __restrict__ att_dst2,
    float* __restrict__ h2, float* __restrict__ a_src2, float* __restrict__ a_dst2, int N) {
    int lane = threadIdx.x & 63;
    int wave = __builtin_amdgcn_readfirstlane((int)((blockIdx.x * 256 + threadIdx.x) >> 6));
    int r0 = wave * R2;
    if (r0 >= N) return;
    int r1 = min(r0 + R2, N);
    bool act = lane < 40;
    float w[64];
#pragma unroll
    for (int k = 0; k < 64; k++) w[k] = act ? W2[k * 40 + lane] : 0.0f;
    float as = act ? att_src2[lane] : 0.0f;
    float ad = act ? att_dst2[lane] : 0.0f;
    for (int r = r0; r < r1; r++) {
        const float4* xr = (const float4*)(xx + (size_t)r * 64);
        float acc = 0.0f;
#pragma unroll
        for (int k4 = 0; k4 < 16; k4++) {
            float4 xv = xr[k4];                                // uniform -> s_load
            acc = fmaf(xv.x, w[4 * k4 + 0], acc);
            acc = fmaf(xv.y, w[4 * k4 + 1], acc);
            acc = fmaf(xv.z, w[4 * k4 + 2], acc);
            acc = fmaf(xv.w, w[4 * k4 + 3], acc);
        }
        if (act) h2[(size_t)r * 40 + lane] = acc;
        float ps = acc * as, pd = acc * ad;
#pragma unroll
        for (int off = 32; off; off >>= 1) {
            ps += __shfl_xor(ps, off);
            pd += __shfl_xor(pd, off);
        }
        if (lane == 0) { a_src2[r] = ps; a_dst2[r] = pd; }
    }
}

// ---------------- layer 2: per-dst-node softmax + aggregate ----------------
__global__ __launch_bounds__(256) void k_node_agg2(
    const int* __restrict__ rowptr, const int* __restrict__ ssrc,
    const float* __restrict__ a_src2, const float* __restrict__ a_dst2,
    const float* __restrict__ h2, const float* __restrict__ bias2,
    float* __restrict__ out, int N) {
    int d = (blockIdx.x * 256 + threadIdx.x) >> 6;
    int lane = threadIdx.x & 63;
    if (d >= N) return;
    int start = rowptr[d], end = rowptr[d + 1];
    float adst = a_dst2[d];
    bool act = lane < 40;
    float acc0 = 0.0f, acc1 = 0.0f, lsumA = 0.0f;
    for (int base = start; base < end; base += 64) {
        int ecnt = min(64, end - base);
        int s_l = 0; float ex_l = 0.0f;
        if (lane < ecnt) {
            s_l = ssrc[base + lane];
            ex_l = __expf(lrelu(a_src2[s_l] + adst));
        }
        lsumA += ex_l;
        int j = 0;
        for (; j + 8 <= ecnt; j += 8) {
            int s0 = __shfl(s_l, j),     s1 = __shfl(s_l, j + 1), s2 = __shfl(s_l, j + 2), s3 = __shfl(s_l, j + 3);
            int s4 = __shfl(s_l, j + 4), s5 = __shfl(s_l, j + 5), s6 = __shfl(s_l, j + 6), s7 = __shfl(s_l, j + 7);
            float f0 = __shfl(ex_l, j),     f1 = __shfl(ex_l, j + 1), f2 = __shfl(ex_l, j + 2), f3 = __shfl(ex_l, j + 3);
            float f4 = __shfl(ex_l, j + 4), f5 = __shfl(ex_l, j + 5), f6 = __shfl(ex_l, j + 6), f7 = __shfl(ex_l, j + 7);
            float g0 = act ? h2[(size_t)s0 * 40 + lane] : 0.0f;
            float g1 = act ? h2[(size_t)s1 * 40 + lane] : 0.0f;
            float g2 = act ? h2[(size_t)s2 * 40 + lane] : 0.0f;
            float g3 = act ? h2[(size_t)s3 * 40 + lane] : 0.0f;
            float g4 = act ? h2[(size_t)s4 * 40 + lane] : 0.0f;
            float g5 = act ? h2[(size_t)s5 * 40 + lane] : 0.0f;
            float g6 = act ? h2[(size_t)s6 * 40 + lane] : 0.0f;
            float g7 = act ? h2[(size_t)s7 * 40 + lane] : 0.0f;
            acc0 = fmaf(f0, g0, acc0); acc1 = fmaf(f1, g1, acc1);
            acc0 = fmaf(f2, g2, acc0); acc1 = fmaf(f3, g3, acc1);
            acc0 = fmaf(f4, g4, acc0); acc1 = fmaf(f5, g5, acc1);
            acc0 = fmaf(f6, g6, acc0); acc1 = fmaf(f7, g7, acc1);
        }
        for (; j < ecnt; j++) {
            int sj = __shfl(s_l, j);
            float fj = __shfl(ex_l, j);
            float g = act ? h2[(size_t)sj * 40 + lane] : 0.0f;
            acc0 = fmaf(fj, g, acc0);
        }
    }
    float t = lsumA;
#pragma unroll
    for (int off = 32; off; off >>= 1) t += __shfl_xor(t, off);
    if (act) out[(size_t)d * 40 + lane] = (acc0 + acc1) / (t + EPS) + bias2[lane];
}

// ---------------- launch ----------------
extern "C" void kernel_launch(void* const* d_in, const int* in_sizes, int n_in,
                              void* d_out, int out_size, void* d_ws, size_t ws_size,
                              hipStream_t stream) {
    const float* x        = (const float*)d_in[0];
    const int*   ei       = (const int*)d_in[1];
    const float* W1       = (const float*)d_in[2];
    const float* att_src1 = (const float*)d_in[3];
    const float* att_dst1 = (const float*)d_in[4];
    const float* bias1    = (const float*)d_in[5];
    const float* W2       = (const float*)d_in[6];
    const float* att_src2 = (const float*)d_in[7];
    const float* att_dst2 = (const float*)d_in[8];
    const float* bias2    = (const float*)d_in[9];
    float* out = (float*)d_out;

    const int N = in_sizes[0] / 128;   // 50000
    const int E = in_sizes[1] / 2;     // 800000
    const int* src = ei;
    const int* dst = ei + E;

    // workspace layout
    float* ws = (float*)d_ws;
    size_t off = 0;
    int*   deg      = (int*)(ws + off); off += (size_t)N;
    int*   rowptr   = (int*)(ws + off); off += (size_t)N + 1;
    int*   cursor   = (int*)(ws + off); off += (size_t)N;
    int*   blocksum = (int*)(ws + off); off += 64;
    int*   blockoff = (int*)(ws + off); off += 64;
    int*   ssrc     = (int*)(ws + off); off += (size_t)E;
    float* h1       = ws + off; off += (size_t)N * 64;
    float* a_src1   = ws + off; off += (size_t)N * 8;
    float* a_dst1   = ws + off; off += (size_t)N * 8;
    float* xx       = ws + off; off += (size_t)N * 64;
    float* h2       = ws + off; off += (size_t)N * 40;
    float* a_src2   = ws + off; off += (size_t)N;
    float* a_dst2   = ws + off; off += (size_t)N;

    const int B = 256;
    auto g = [](int n) { return (n + 255) / 256; };
    int nb = (N + 1023) / 1024;   // 49

    // CSR build (dst-grouped)
    k_zero<<<g(N), B, 0, stream>>>(deg, N);
    k_deg<<<g(E), B, 0, stream>>>(dst, deg, E);
    k_scan_local<<<nb, 1024, 0, stream>>>(deg, rowptr, blocksum, N);
    k_scan_sums<<<1, 64, 0, stream>>>(blocksum, blockoff, nb);
    k_scan_add<<<g(N), B, 0, stream>>>(rowptr, blockoff, deg, cursor, N);
    k_scatter<<<g(E), B, 0, stream>>>(src, dst, cursor, ssrc, E);

    // layer 1
    int waves1 = (N + R1 - 1) / R1;
    k_gemm1<<<(waves1 + 3) / 4, B, 0, stream>>>(x, W1, att_src1, att_dst1, h1, a_src1, a_dst1, N);
    k_node_agg1<<<(N + 3) / 4, B, 0, stream>>>(rowptr, ssrc, a_src1, a_dst1, h1, bias1, xx, N);

    // layer 2 (gemm + attn dots fused)
    int waves2 = (N + R2 - 1) / R2;
    k_gemm2<<<(waves2 + 3) / 4, B, 0, stream>>>(xx, W2, att_src2, att_dst2, h2, a_src2, a_dst2, N);
    k_node_agg2<<<(N + 3) / 4, B, 0, stream>>>(rowptr, ssrc, a_src2, a_dst2, h2, bias2, out, N);
}